// Round 2
// baseline (597.438 us; speedup 1.0000x reference)
//
#include <hip/hip_runtime.h>
#include <hip/hip_bf16.h>

#define NN 4096
#define EE 2048
#define RR 4
#define FF 128
#define HDD 256

typedef __attribute__((ext_vector_type(4))) float floatx4;
typedef __attribute__((ext_vector_type(8))) __bf16 bf16x8;
typedef __attribute__((ext_vector_type(8))) unsigned short ushort8;

#define AS1 __attribute__((address_space(1)))
#define AS3 __attribute__((address_space(3)))

__device__ __forceinline__ void async16(const void* g, void* l) {
  // global -> LDS direct copy, 16B per lane; LDS dest = wave-uniform base + lane*16
  __builtin_amdgcn_global_load_lds((const AS1 void*)(unsigned long long)(g),
                                   (AS3 void*)(unsigned int)(unsigned long long)(l),
                                   16, 0, 0);
}

__device__ inline unsigned short f2b(float x) {
  unsigned int u = __float_as_uint(x);
  unsigned int r = u + 0x7fffu + ((u >> 16) & 1u);
  return (unsigned short)(r >> 16);
}
__device__ inline float b2f(unsigned short u) { return __uint_as_float((unsigned int)u << 16); }

__device__ inline float rel_w(const float* rel, int r) {
  float m = fmaxf(fmaxf(rel[0], rel[1]), fmaxf(rel[2], rel[3]));
  float s = 0.f;
#pragma unroll
  for (int i = 0; i < RR; i++) s += expf(rel[i] - m);
  return expf(rel[r] - m) / s;
}

// ---- single pass over H: row sums -> dvs[r][n] = rw*rsqrt(rw*sum+eps), plus mask1[r][n][e/64] ----
// bit l of word w  <->  e = w*64 + l
__global__ void k_dvmask(const float* __restrict__ H, const float* __restrict__ rel,
                         float* __restrict__ dvs, unsigned long long* __restrict__ mask) {
  int wave = (blockIdx.x << 2) | (threadIdx.x >> 6);  // = r*NN + n
  int lane = threadIdx.x & 63;
  int r = wave >> 12;
  const float* row = H + (size_t)wave * EE;
  unsigned long long* mrow = mask + (size_t)wave * (EE / 64);
  float s = 0.f;
  for (int j = 0; j < EE / 64; j++) {
    float h = row[j * 64 + lane];
    s += h;
    unsigned long long m = __ballot(h != 0.0f);
    if (lane == 0) mrow[j] = m;
  }
  for (int off = 32; off; off >>= 1) s += __shfl_down(s, off);
  if (lane == 0) {
    float rwr = rel_w(rel, r);
    dvs[wave] = rwr * rsqrtf(rwr * s + 1e-8f);
  }
}

// ---- bit-transpose mask1 -> mask2[r][e][n/64] (bit l of word v <-> n = v*64+l), plus de counts ----
__global__ void k_maskT(const unsigned long long* __restrict__ m1, unsigned long long* __restrict__ m2,
                        float* __restrict__ de) {
  __shared__ unsigned long long w[64 * 33];
  int r = blockIdx.x >> 6;             // 64 blocks per r, each owns 64 n's
  int n0 = (blockIdx.x & 63) << 6;
  int t = threadIdx.x;
  const unsigned long long* src = m1 + ((size_t)r * NN + n0) * 32;
#pragma unroll
  for (int i = 0; i < 8; i++) {
    int idx = t + i * 256;             // 2048 words, coalesced
    int n = idx >> 5, W = idx & 31;
    w[n * 33 + W] = src[idx];
  }
  __syncthreads();
  int wid = t >> 6, lane = t & 63;
  int v = n0 >> 6;
#pragma unroll
  for (int Wi = 0; Wi < 8; Wi++) {
    int W = wid * 8 + Wi;
    unsigned long long myw = w[lane * 33 + W];
    unsigned long long out = 0;
    for (int b = 0; b < 64; b++) {
      unsigned long long mm = __ballot(((myw >> b) & 1ULL) != 0);
      if (lane == b) out = mm;
    }
    // lane holds n-bits for e = W*64+lane
    m2[((size_t)r * EE + W * 64 + lane) * 64 + v] = out;
    atomicAdd(&de[r * EE + W * 64 + lane], (float)__popcll(out));
  }
}

// ---- deR[r][e] = rsqrt(rw*cnt + eps) ----
__global__ void k_deR(const float* __restrict__ de, const float* __restrict__ rel, float* __restrict__ deR) {
  int i = blockIdx.x * 256 + threadIdx.x;
  int r = i >> 11;
  float rwr = rel_w(rel, r);
  deR[i] = rsqrtf(rwr * de[i] + 1e-8f);
}

// ---- f32 [M][C] -> bf16 [C][M] (transpose+convert) ----
__global__ void k_cvtT(const float* __restrict__ src, unsigned short* __restrict__ dst, int M, int C) {
  __shared__ unsigned short tile[64][65];
  int c0 = blockIdx.x * 64, m0 = blockIdx.y * 64;
  int tr = threadIdx.x >> 4, tc = threadIdx.x & 15;
#pragma unroll
  for (int i = 0; i < 4; i++) {
    int m = m0 + tr + 16 * i;
    float4 v = *(const float4*)(src + (size_t)m * C + c0 + tc * 4);
    tile[tr + 16 * i][tc * 4 + 0] = f2b(v.x);
    tile[tr + 16 * i][tc * 4 + 1] = f2b(v.y);
    tile[tr + 16 * i][tc * 4 + 2] = f2b(v.z);
    tile[tr + 16 * i][tc * 4 + 3] = f2b(v.w);
  }
  __syncthreads();
#pragma unroll
  for (int i = 0; i < 4; i++) {
    int c = c0 + tr + 16 * i;
    ushort4 v;
    v.x = tile[tc * 4 + 0][tr + 16 * i];
    v.y = tile[tc * 4 + 1][tr + 16 * i];
    v.z = tile[tc * 4 + 2][tr + 16 * i];
    v.w = tile[tc * 4 + 3][tr + 16 * i];
    *(ushort4*)(dst + (size_t)c * M + m0 + tc * 4) = v;
  }
}

// ---- bf16 [M][C] -> bf16 [C][M] ----
__global__ void k_trz(const unsigned short* __restrict__ src, unsigned short* __restrict__ dst, int M, int C) {
  __shared__ unsigned short tile[64][65];
  int c0 = blockIdx.x * 64, m0 = blockIdx.y * 64;
  int tr = threadIdx.x >> 4, tc = threadIdx.x & 15;
#pragma unroll
  for (int i = 0; i < 4; i++) {
    int m = m0 + tr + 16 * i;
    ushort4 v = *(const ushort4*)(src + (size_t)m * C + c0 + tc * 4);
    tile[tr + 16 * i][tc * 4 + 0] = v.x;
    tile[tr + 16 * i][tc * 4 + 1] = v.y;
    tile[tr + 16 * i][tc * 4 + 2] = v.z;
    tile[tr + 16 * i][tc * 4 + 3] = v.w;
  }
  __syncthreads();
#pragma unroll
  for (int i = 0; i < 4; i++) {
    int c = c0 + tr + 16 * i;
    ushort4 v;
    v.x = tile[tc * 4 + 0][tr + 16 * i];
    v.y = tile[tc * 4 + 1][tr + 16 * i];
    v.z = tile[tc * 4 + 2][tr + 16 * i];
    v.w = tile[tc * 4 + 3][tr + 16 * i];
    *(ushort4*)(dst + (size_t)c * M + m0 + tc * 4) = v;
  }
}

// ---- all three weight transforms in ONE launch ----
__global__ void k_wprep(const float* __restrict__ W1, const float* __restrict__ W2,
                        const float* __restrict__ W3, const float* __restrict__ imp,
                        unsigned short* __restrict__ W1catT, unsigned short* __restrict__ W2T,
                        unsigned short* __restrict__ W3T) {
  int idx = blockIdx.x * 256 + threadIdx.x;
  if (idx < RR * FF * HDD) {
    int o = idx % HDD, f = (idx / HDD) % FF, r = idx / (HDD * FF);
    float sg = 1.0f / (1.0f + expf(-imp[r]));
    W1catT[(size_t)o * (RR * FF) + r * FF + f] = f2b(sg * W1[((size_t)r * FF + f) * HDD + o]);
  } else if (idx < RR * FF * HDD + RR * HDD * HDD) {
    int j = idx - RR * FF * HDD;
    int c = j % HDD, o = (j / HDD) % HDD, r = j / (HDD * HDD);
    float sg = 1.0f / (1.0f + expf(-imp[RR + r]));
    W2T[j] = f2b(sg * W2[((size_t)r * HDD + c) * HDD + o]);
  } else {
    int j = idx - RR * FF * HDD - RR * HDD * HDD;
    int c = j % HDD, o = (j / HDD) % FF, r = j / (HDD * FF);
    float sg = 1.0f / (1.0f + expf(-imp[2 * RR + r]));
    W3T[j] = f2b(sg * W3[((size_t)r * HDD + c) * FF + o]);
  }
}

// ---------------- MFMA GEMM, 128x128 tile, BK=64, async staging (XOR swizzle) ----------------
// DECA/DECB: that operand is NOT read from memory; its tile is decoded from a bitmask:
//   value(row, k) = bit(row,k) ? alpha[row]*beta[k] : 0   (bf16, identical numerics to old build)
// mask word: dm[(zr*drow_rs + rowbase + row)*dnw + (kglob>>6)], bit (kglob&63)
// z = zr*SK + kz. Partial C at P + kz*c_ps + zr*c_rs.
template <int DECA, int DECB>
__global__ __launch_bounds__(256) void k_gemm3(
    const unsigned short* __restrict__ A, const unsigned short* __restrict__ BT,
    int K, int SK, int lda, int ldb, long a_rs, long b_rs,
    unsigned short* __restrict__ P, long c_ps, long c_rs, int ldc,
    const unsigned long long* __restrict__ dm, int dnw,
    const float* __restrict__ dal, const float* __restrict__ dbe, long drow_rs, long dbe_rs) {
  __shared__ unsigned short Al[128 * 64];
  __shared__ unsigned short Bl[128 * 64];
  int tid = threadIdx.x, wid = tid >> 6, lane = tid & 63;
  int m0 = blockIdx.x << 7, n0 = blockIdx.y << 7;
  int z = blockIdx.z, zr = z / SK, kz = z - zr * SK;
  int Kc = K / SK;
  int r8 = lane >> 3, c8 = lane & 7;
  int swz = ((c8 ^ r8) << 3);               // element offset of this lane's 16B chunk within the row
  const unsigned short* Ab = A + (DECA ? 0 : ((size_t)zr * a_rs + (size_t)m0 * lda + (size_t)kz * Kc));
  const unsigned short* Bb = BT + (DECB ? 0 : ((size_t)zr * b_rs + (size_t)n0 * ldb + (size_t)kz * Kc));
  // decode setup (one operand at most)
  int drow = tid >> 1, dhalf = tid & 1;
  long rowOff = (long)zr * drow_rs + (DECA ? m0 : n0) + drow;
  float dalpha = (DECA || DECB) ? dal[rowOff] : 0.f;
  const float* dbeta = (DECA || DECB) ? (dbe + (long)zr * dbe_rs) : nullptr;
  int dsw = drow & 7;
  unsigned short* Dl = DECA ? Al : Bl;

  int wm = (wid >> 1) << 6, wn = (wid & 1) << 6;
  int fm = lane & 15, quad = lane >> 4;
  int f7 = fm & 7;
  floatx4 acc[4][4];
#pragma unroll
  for (int i = 0; i < 4; i++)
#pragma unroll
    for (int j = 0; j < 4; j++) acc[i][j] = (floatx4){0.f, 0.f, 0.f, 0.f};
  for (int k0 = 0; k0 < Kc; k0 += 64) {
    if (!DECA) {
#pragma unroll
      for (int t = 0; t < 4; t++) {
        int rbase = (wid << 5) + (t << 3);
        int row = rbase + r8;
        async16(Ab + (size_t)row * lda + k0 + swz, &Al[rbase * 64 + lane * 8]);
      }
    }
    if (!DECB) {
#pragma unroll
      for (int t = 0; t < 4; t++) {
        int rbase = (wid << 5) + (t << 3);
        int row = rbase + r8;
        async16(Bb + (size_t)row * ldb + k0 + swz, &Bl[rbase * 64 + lane * 8]);
      }
    }
    if (DECA || DECB) {
      long kglob = (long)kz * Kc + k0;
      const unsigned int* wp = (const unsigned int*)(dm + (size_t)rowOff * dnw + (kglob >> 6));
      unsigned int bits = wp[dhalf];
      const float* bp = dbeta + kglob + dhalf * 32;
#pragma unroll
      for (int g = 0; g < 4; g++) {
        float4 p0 = *(const float4*)(bp + g * 8);
        float4 p1 = *(const float4*)(bp + g * 8 + 4);
        unsigned int bb = bits >> (g * 8);
        ushort8 v;
        v[0] = (bb & 1u)   ? f2b(dalpha * p0.x) : (unsigned short)0;
        v[1] = (bb & 2u)   ? f2b(dalpha * p0.y) : (unsigned short)0;
        v[2] = (bb & 4u)   ? f2b(dalpha * p0.z) : (unsigned short)0;
        v[3] = (bb & 8u)   ? f2b(dalpha * p0.w) : (unsigned short)0;
        v[4] = (bb & 16u)  ? f2b(dalpha * p1.x) : (unsigned short)0;
        v[5] = (bb & 32u)  ? f2b(dalpha * p1.y) : (unsigned short)0;
        v[6] = (bb & 64u)  ? f2b(dalpha * p1.z) : (unsigned short)0;
        v[7] = (bb & 128u) ? f2b(dalpha * p1.w) : (unsigned short)0;
        int chunk = ((dhalf << 2) | g) ^ dsw;   // place global chunk at pos chunk^ (row&7): reader-compatible
        *(ushort8*)&Dl[drow * 64 + chunk * 8] = v;
      }
    }
    __syncthreads();  // drains vmcnt (async16) + lgkm (decode ds_writes)
#pragma unroll
    for (int ks = 0; ks < 2; ks++) {
      int kg = (ks << 2) | quad;
      int ko = ((kg ^ f7) << 3);
      bf16x8 a[4], b[4];
#pragma unroll
      for (int i = 0; i < 4; i++) {
        a[i] = *(const bf16x8*)&Al[(wm + i * 16 + fm) * 64 + ko];
        b[i] = *(const bf16x8*)&Bl[(wn + i * 16 + fm) * 64 + ko];
      }
#pragma unroll
      for (int i = 0; i < 4; i++)
#pragma unroll
        for (int j = 0; j < 4; j++)
          acc[i][j] = __builtin_amdgcn_mfma_f32_16x16x32_bf16(a[i], b[j], acc[i][j], 0, 0, 0);
    }
    __syncthreads();
  }
  unsigned short* Cb = P + (size_t)kz * c_ps + (size_t)zr * c_rs;
#pragma unroll
  for (int mi = 0; mi < 4; mi++)
#pragma unroll
    for (int ni = 0; ni < 4; ni++)
#pragma unroll
      for (int v = 0; v < 4; v++) {
        int row = m0 + wm + mi * 16 + quad * 4 + v;
        int col = n0 + wn + ni * 16 + fm;
        Cb[(size_t)row * ldc + col] = f2b(acc[mi][ni][v]);
      }
}

// ---- reduce SK bf16 partials per zr -> bf16 out[zr][region] ----
__global__ void k_red_b(const unsigned short* __restrict__ P, unsigned short* __restrict__ out,
                        int SK, long region) {
  long i = ((long)blockIdx.x * 256 + threadIdx.x) * 8;
  int zr = blockIdx.y;
  const unsigned short* p = P + (size_t)zr * SK * region + i;
  float s[8] = {0, 0, 0, 0, 0, 0, 0, 0};
  for (int k = 0; k < SK; k++) {
    const unsigned short* q = p + (size_t)k * region;
    ushort4 a = *(const ushort4*)q;
    ushort4 b = *(const ushort4*)(q + 4);
    s[0] += b2f(a.x); s[1] += b2f(a.y); s[2] += b2f(a.z); s[3] += b2f(a.w);
    s[4] += b2f(b.x); s[5] += b2f(b.y); s[6] += b2f(b.z); s[7] += b2f(b.w);
  }
  ushort4 o0, o1;
  o0.x = f2b(s[0]); o0.y = f2b(s[1]); o0.z = f2b(s[2]); o0.w = f2b(s[3]);
  o1.x = f2b(s[4]); o1.y = f2b(s[5]); o1.z = f2b(s[6]); o1.w = f2b(s[7]);
  unsigned short* d = out + (size_t)zr * region + i;
  *(ushort4*)d = o0;
  *(ushort4*)(d + 4) = o1;
}

// ---- reduce SK bf16 partials per r of [NN][FF] -> Hcat[n][r*FF+f] bf16 ----
__global__ void k_red_hcatb(const unsigned short* __restrict__ P, unsigned short* __restrict__ out, int SK) {
  long i = ((long)blockIdx.x * 256 + threadIdx.x) * 8;
  int r = blockIdx.y;
  const unsigned short* p = P + (size_t)r * SK * (NN * FF) + i;
  float s[8] = {0, 0, 0, 0, 0, 0, 0, 0};
  for (int k = 0; k < SK; k++) {
    const unsigned short* q = p + (size_t)k * (NN * FF);
    ushort4 a = *(const ushort4*)q;
    ushort4 b = *(const ushort4*)(q + 4);
    s[0] += b2f(a.x); s[1] += b2f(a.y); s[2] += b2f(a.z); s[3] += b2f(a.w);
    s[4] += b2f(b.x); s[5] += b2f(b.y); s[6] += b2f(b.z); s[7] += b2f(b.w);
  }
  long n = i >> 7;
  int f = (int)(i & 127);
  ushort4 o0, o1;
  o0.x = f2b(s[0]); o0.y = f2b(s[1]); o0.z = f2b(s[2]); o0.w = f2b(s[3]);
  o1.x = f2b(s[4]); o1.y = f2b(s[5]); o1.z = f2b(s[6]); o1.w = f2b(s[7]);
  unsigned short* d = out + n * (RR * FF) + r * FF + f;
  *(ushort4*)d = o0;
  *(ushort4*)(d + 4) = o1;
}

// ---- reduce Z bf16 partials of [NN][HDD] -> convout f32 + fused BN column stats ----
__global__ void k_redstats(const unsigned short* __restrict__ P, float* __restrict__ out,
                           float* __restrict__ cs, float* __restrict__ cs2, int Z) {
  __shared__ float sm[2][8][256];
  int cg = (threadIdx.x & 31) << 3;
  int rowt = threadIdx.x >> 5;
  int r0 = blockIdx.x * 32;
  float s[8] = {0, 0, 0, 0, 0, 0, 0, 0}, s2[8] = {0, 0, 0, 0, 0, 0, 0, 0};
  for (int j = 0; j < 4; j++) {
    long idx = (long)(r0 + rowt * 4 + j) * HDD + cg;
    float acc[8] = {0, 0, 0, 0, 0, 0, 0, 0};
    for (int z = 0; z < Z; z++) {
      const unsigned short* p = P + (size_t)z * ((long)NN * HDD) + idx;
      ushort4 a = *(const ushort4*)p;
      ushort4 b = *(const ushort4*)(p + 4);
      acc[0] += b2f(a.x); acc[1] += b2f(a.y); acc[2] += b2f(a.z); acc[3] += b2f(a.w);
      acc[4] += b2f(b.x); acc[5] += b2f(b.y); acc[6] += b2f(b.z); acc[7] += b2f(b.w);
    }
    float4 o0 = {acc[0], acc[1], acc[2], acc[3]};
    float4 o1 = {acc[4], acc[5], acc[6], acc[7]};
    *(float4*)(out + idx) = o0;
    *(float4*)(out + idx + 4) = o1;
#pragma unroll
    for (int i = 0; i < 8; i++) { s[i] += acc[i]; s2[i] += acc[i] * acc[i]; }
  }
#pragma unroll
  for (int i = 0; i < 8; i++) { sm[0][rowt][cg + i] = s[i]; sm[1][rowt][cg + i] = s2[i]; }
  __syncthreads();
  int c = threadIdx.x;
  float a0 = 0, a1 = 0;
#pragma unroll
  for (int t = 0; t < 8; t++) { a0 += sm[0][t][c]; a1 += sm[1][t][c]; }
  atomicAdd(&cs[c], a0);
  atomicAdd(&cs2[c], a1);
}

// ---- final: d_out = X + b3 + sum_Z bf16 partials [Z][NN][FF] ----
__global__ void k_red_out(const unsigned short* __restrict__ P, const float* __restrict__ X,
                          const float* __restrict__ b3, float* __restrict__ out, int Z) {
  long i = ((long)blockIdx.x * 256 + threadIdx.x) * 4;
  int f = (int)(i & 127);
  float4 s = *(const float4*)(X + i);
  s.x += b3[f]; s.y += b3[f + 1]; s.z += b3[f + 2]; s.w += b3[f + 3];
  for (int z = 0; z < Z; z++) {
    ushort4 v = *(const ushort4*)(P + (size_t)z * (NN * FF) + i);
    s.x += b2f(v.x); s.y += b2f(v.y); s.z += b2f(v.z); s.w += b2f(v.w);
  }
  *(float4*)(out + i) = s;
}

// ---- BN (batch stats) -> LN -> ELU -> bf16 [NN][HDD] ----
__global__ void k_bnlnelu(const float* __restrict__ x, const float* __restrict__ cs, const float* __restrict__ cs2,
                          const float* __restrict__ bg, const float* __restrict__ bb,
                          const float* __restrict__ lg, const float* __restrict__ lb,
                          unsigned short* __restrict__ out) {
  int wid = threadIdx.x >> 6, lane = threadIdx.x & 63;
  int n = blockIdx.x * 4 + wid;
  float y[4];
  float m = 0.f;
#pragma unroll
  for (int j = 0; j < 4; j++) {
    int c = lane + 64 * j;
    float mu = cs[c] * (1.0f / NN);
    float var = cs2[c] * (1.0f / NN) - mu * mu;
    float xv = x[(size_t)n * HDD + c];
    y[j] = (xv - mu) * rsqrtf(var + 1e-5f) * bg[c] + bb[c];
    m += y[j];
  }
  for (int off = 32; off; off >>= 1) m += __shfl_down(m, off);
  m = __shfl(m, 0) * (1.0f / HDD);
  float var = 0.f;
#pragma unroll
  for (int j = 0; j < 4; j++) { float d = y[j] - m; var += d * d; }
  for (int off = 32; off; off >>= 1) var += __shfl_down(var, off);
  var = __shfl(var, 0) * (1.0f / HDD);
  float inv = rsqrtf(var + 1e-5f);
#pragma unroll
  for (int j = 0; j < 4; j++) {
    int c = lane + 64 * j;
    float z = (y[j] - m) * inv * lg[c] + lb[c];
    z = z > 0.f ? z : expm1f(z);
    out[(size_t)n * HDD + c] = f2b(z);
  }
}

extern "C" void kernel_launch(void* const* d_in, const int* in_sizes, int n_in,
                              void* d_out, int out_size, void* d_ws, size_t ws_size,
                              hipStream_t stream) {
  const float* X   = (const float*)d_in[0];
  const float* H   = (const float*)d_in[1];
  const float* W1  = (const float*)d_in[2];
  const float* W2  = (const float*)d_in[3];
  const float* W3  = (const float*)d_in[4];
  const float* imp = (const float*)d_in[5];
  const float* b3  = (const float*)d_in[8];
  const float* bng = (const float*)d_in[9];
  const float* bnb = (const float*)d_in[10];
  const float* lng = (const float*)d_in[11];
  const float* lnb = (const float*)d_in[12];
  const float* rel = (const float*)d_in[13];
  (void)in_sizes; (void)n_in; (void)out_size; (void)ws_size;

  char* w = (char*)d_ws;
  size_t off = 0;
  auto alloc = [&](size_t bytes) -> void* {
    void* p = w + off;
    off += (bytes + 255) & ~(size_t)255;
    return p;
  };
  float* dvs  = (float*)alloc((size_t)RR * NN * 4);
  float* de   = (float*)alloc((size_t)RR * EE * 4);       // raw column counts
  float* deR  = (float*)alloc((size_t)RR * EE * 4);       // rsqrt(rw*cnt+eps)
  float* cs   = (float*)alloc(2 * HDD * 4);               // [cs | cs2]
  unsigned long long* mask1 = (unsigned long long*)alloc((size_t)RR * NN * (EE / 64) * 8);  // 4MB
  unsigned long long* mask2 = (unsigned long long*)alloc((size_t)RR * EE * (NN / 64) * 8);  // 4MB
  unsigned short* bufP = (unsigned short*)alloc((size_t)16 * NN * HDD * 2);    // 32MB bf16 partials
  unsigned short* bufC = (unsigned short*)alloc((size_t)RR * EE * HDD * 2);    // 4MB
  unsigned short* bufD = (unsigned short*)alloc((size_t)RR * EE * HDD * 2);    // 4MB
  unsigned short* bufE = (unsigned short*)alloc((size_t)RR * EE * HDD * 2);    // 4MB
  float* convout = (float*)alloc((size_t)NN * HDD * 4);                        // 4MB
  unsigned short* Xb  = (unsigned short*)alloc((size_t)NN * HDD * 2);
  unsigned short* XbT = (unsigned short*)alloc((size_t)NN * HDD * 2);
  unsigned short* W1catT = (unsigned short*)alloc((size_t)RR * FF * HDD * 2);
  unsigned short* W2T    = (unsigned short*)alloc((size_t)RR * HDD * HDD * 2);
  unsigned short* W3T    = (unsigned short*)alloc((size_t)RR * HDD * FF * 2);

  // ---- prep ----
  k_dvmask<<<(RR * NN) / 4, 256, 0, stream>>>(H, rel, dvs, mask1);
  hipMemsetAsync(de, 0, (size_t)RR * EE * 4, stream);
  k_maskT<<<RR * (NN / 64), 256, 0, stream>>>(mask1, mask2, de);
  k_deR<<<(RR * EE) / 256, 256, 0, stream>>>(de, rel, deR);
  k_cvtT<<<dim3(FF / 64, NN / 64), 256, 0, stream>>>(X, XbT, NN, FF);  // XbT [128][4096]
  k_wprep<<<(RR * FF * HDD + RR * HDD * HDD + RR * HDD * FF) / 256, 256, 0, stream>>>(
      W1, W2, W3, imp, W1catT, W2T, W3T);

  // ---- layer 1 (128 -> 256) ----
  // tT[r][f][e] = sum_n XbT[f][n] thetaT[r][e][n]   M=128,N=2048,K=4096, z=(r,SK8)
  // B decoded from mask2: alpha=deR[r*EE+e], beta=dvs[r*NN+n]
  k_gemm3<0, 1><<<dim3(1, EE / 128, RR * 8), 256, 0, stream>>>(
      XbT, nullptr, NN, 8, NN, 0, 0, 0, bufP, (long)FF * EE, 8L * FF * EE, EE,
      mask2, NN / 64, deR, dvs, EE, NN);
  k_red_b<<<dim3((FF * EE) / 2048, RR), 256, 0, stream>>>(bufP, bufC, 8, (long)FF * EE);  // tTb [r][f][e]
  // Hcat[n][r*128+f] = sum_e theta[r][n][e] tTb[r][f][e]   M=4096,N=128,K=2048, z=(r,SK2)
  // A decoded from mask1: alpha=dvs[r*NN+n], beta=deR[r*EE+e]
  k_gemm3<1, 0><<<dim3(NN / 128, 1, RR * 2), 256, 0, stream>>>(
      nullptr, bufC, EE, 2, 0, EE, 0, (long)FF * EE, bufP, (long)NN * FF, 2L * NN * FF, FF,
      mask1, EE / 64, dvs, deR, NN, EE);
  k_red_hcatb<<<dim3((NN * FF) / 2048, RR), 256, 0, stream>>>(bufP, bufD, 2);  // Hcatb [4096][512]
  // convout = Hcatb @ W1cat   M=4096,N=256,K=512, SK=4 (b1 dropped: BN-invariant)
  k_gemm3<0, 0><<<dim3(NN / 128, HDD / 128, 4), 256, 0, stream>>>(
      bufD, W1catT, RR * FF, 4, RR * FF, RR * FF, 0, 0, bufP, (long)NN * HDD, 4L * NN * HDD, HDD,
      nullptr, 0, nullptr, nullptr, 0, 0);
  hipMemsetAsync(cs, 0, 2 * HDD * 4, stream);
  k_redstats<<<NN / 32, 256, 0, stream>>>(bufP, convout, cs, cs + HDD, 4);
  k_bnlnelu<<<NN / 4, 256, 0, stream>>>(convout, cs, cs + HDD, bng, bnb, lng, lnb, Xb);
  k_trz<<<dim3(HDD / 64, NN / 64), 256, 0, stream>>>(Xb, XbT, NN, HDD);  // h^T [256][4096]

  // ---- layer 2 (256 -> 256) ----
  // t2[r*EE+e][c] = sum_n thetaT[r][e][n] h^T[c][n]   per-r M=2048,N=256,K=4096, z=(r,SK4)
  // A decoded from mask2; partial kz covers full [8192][256]: c_ps=RR*EE*HDD, row block via c_rs=EE*HDD
  k_gemm3<1, 0><<<dim3(EE / 128, HDD / 128, RR * 4), 256, 0, stream>>>(
      nullptr, XbT, NN, 4, 0, NN, 0, 0, bufP, (long)RR * EE * HDD, (long)EE * HDD, HDD,
      mask2, NN / 64, deR, dvs, EE, NN);
  k_red_b<<<dim3((RR * EE * HDD) / 2048, 1), 256, 0, stream>>>(bufP, bufD, 4, (long)RR * EE * HDD);  // t2b [r][e][c]
  // uT[r][o][e] = sum_c W2T[r][o][c] t2b[r][e][c]   M=256,N=2048,K=256, SK=1, z=r, direct bf16 write
  k_gemm3<0, 0><<<dim3(HDD / 128, EE / 128, RR), 256, 0, stream>>>(
      W2T, bufD, HDD, 1, HDD, HDD, (long)HDD * HDD, (long)EE * HDD, bufE, (long)HDD * EE, (long)HDD * EE, EE,
      nullptr, 0, nullptr, nullptr, 0, 0);
  // convout[n][o] = sum_r sum_e theta[r][n][e] uT[r][o][e]   M=4096,N=256,K=2048, z=(r,SK2)
  k_gemm3<1, 0><<<dim3(NN / 128, HDD / 128, RR * 2), 256, 0, stream>>>(
      nullptr, bufE, EE, 2, 0, EE, 0, (long)HDD * EE, bufP, (long)NN * HDD, 2L * NN * HDD, HDD,
      mask1, EE / 64, dvs, deR, NN, EE);
  hipMemsetAsync(cs, 0, 2 * HDD * 4, stream);
  k_redstats<<<NN / 32, 256, 0, stream>>>(bufP, convout, cs, cs + HDD, 8);
  k_bnlnelu<<<NN / 4, 256, 0, stream>>>(convout, cs, cs + HDD, bng + HDD, bnb + HDD, lng + HDD, lnb + HDD, Xb);

  // ---- layer 3 (256 -> 128), W3 applied first ----
  // yT[r][f][n] = sum_c W3T[r][f][c] Xb[n][c]   M=128,N=4096,K=256, SK=1, z=r, direct bf16 write
  k_gemm3<0, 0><<<dim3(1, NN / 128, RR), 256, 0, stream>>>(
      W3T, Xb, HDD, 1, HDD, HDD, (long)FF * HDD, 0, bufD, (long)FF * NN, (long)FF * NN, NN,
      nullptr, 0, nullptr, nullptr, 0, 0);
  // sT[r][f][e] = sum_n yT[r][f][n] thetaT[r][e][n]   M=128,N=2048,K=4096, z=(r,SK4)
  // B decoded from mask2
  k_gemm3<0, 1><<<dim3(1, EE / 128, RR * 4), 256, 0, stream>>>(
      bufD, nullptr, NN, 4, NN, 0, (long)FF * NN, 0, bufP, (long)FF * EE, 4L * FF * EE, EE,
      mask2, NN / 64, deR, dvs, EE, NN);
  k_red_b<<<dim3((FF * EE) / 2048, RR), 256, 0, stream>>>(bufP, bufC, 4, (long)FF * EE);  // sTb [r][f][e]
  // P[z] = theta[r] @ sTb[r] chunks   M=4096,N=128,K=2048, z=(r,SK2)
  k_gemm3<1, 0><<<dim3(NN / 128, 1, RR * 2), 256, 0, stream>>>(
      nullptr, bufC, EE, 2, 0, EE, 0, (long)FF * EE, bufP, (long)NN * FF, 2L * NN * FF, FF,
      mask1, EE / 64, dvs, deR, NN, EE);
  // d_out = X + b3 + sum_z P[z]
  k_red_out<<<(NN * FF) / 1024, 256, 0, stream>>>(bufP, X, b3, (float*)d_out, 8);
}

// Round 3
// 491.397 us; speedup vs baseline: 1.2158x; 1.2158x over previous
//
#include <hip/hip_runtime.h>
#include <hip/hip_bf16.h>

#define NN 4096
#define EE 2048
#define RR 4
#define FF 128
#define HDD 256

typedef __attribute__((ext_vector_type(4))) float floatx4;
typedef __attribute__((ext_vector_type(8))) __bf16 bf16x8;

#define AS1 __attribute__((address_space(1)))
#define AS3 __attribute__((address_space(3)))

__device__ __forceinline__ void async16(const void* g, void* l) {
  __builtin_amdgcn_global_load_lds((const AS1 void*)(unsigned long long)(g),
                                   (AS3 void*)(unsigned int)(unsigned long long)(l),
                                   16, 0, 0);
}

__device__ inline unsigned short f2b(float x) {
  unsigned int u = __float_as_uint(x);
  unsigned int r = u + 0x7fffu + ((u >> 16) & 1u);
  return (unsigned short)(r >> 16);
}
__device__ inline float b2f(unsigned short u) { return __uint_as_float((unsigned int)u << 16); }

__device__ inline float rel_w(const float* rel, int r) {
  float m = fmaxf(fmaxf(rel[0], rel[1]), fmaxf(rel[2], rel[3]));
  float s = 0.f;
#pragma unroll
  for (int i = 0; i < RR; i++) s += expf(rel[i] - m);
  return expf(rel[r] - m) / s;
}

// ---- single pass over H: row sums -> dvs[r][n], plus canonical mask1[r][n][e/64] ----
// bit l of word j  <->  e = j*64 + l
__global__ void k_dvmask(const float* __restrict__ H, const float* __restrict__ rel,
                         float* __restrict__ dvs, unsigned long long* __restrict__ mask) {
  int wave = (blockIdx.x << 2) | (threadIdx.x >> 6);  // = r*NN + n
  int lane = threadIdx.x & 63;
  int r = wave >> 12;
  const float* row = H + (size_t)wave * EE;
  unsigned long long* mrow = mask + (size_t)wave * (EE / 64);
  float s = 0.f;
  for (int j = 0; j < EE / 64; j++) {
    float h = row[j * 64 + lane];
    s += h;
    unsigned long long m = __ballot(h != 0.0f);
    if (lane == 0) mrow[j] = m;
  }
  for (int off = 32; off; off >>= 1) s += __shfl_down(s, off);
  if (lane == 0) {
    float rwr = rel_w(rel, r);
    dvs[wave] = rwr * rsqrtf(rwr * s + 1e-8f);
  }
}

// ---- bit-transpose mask1 -> mask2[r][e][n/64] (bit l of word v <-> n = v*64+l), plus de counts ----
__global__ void k_maskT(const unsigned long long* __restrict__ m1, unsigned long long* __restrict__ m2,
                        float* __restrict__ de) {
  __shared__ unsigned long long w[64 * 33];
  int r = blockIdx.x >> 6;
  int n0 = (blockIdx.x & 63) << 6;
  int t = threadIdx.x;
  const unsigned long long* src = m1 + ((size_t)r * NN + n0) * 32;
#pragma unroll
  for (int i = 0; i < 8; i++) {
    int idx = t + i * 256;
    int n = idx >> 5, W = idx & 31;
    w[n * 33 + W] = src[idx];
  }
  __syncthreads();
  int wid = t >> 6, lane = t & 63;
  int v = n0 >> 6;
#pragma unroll
  for (int Wi = 0; Wi < 8; Wi++) {
    int W = wid * 8 + Wi;
    unsigned long long myw = w[lane * 33 + W];
    unsigned long long out = 0;
    for (int b = 0; b < 64; b++) {
      unsigned long long mm = __ballot(((myw >> b) & 1ULL) != 0);
      if (lane == b) out = mm;
    }
    m2[((size_t)r * EE + W * 64 + lane) * 64 + v] = out;
    atomicAdd(&de[r * EE + W * 64 + lane], (float)__popcll(out));
  }
}

// ---- deR[r][e] = rsqrt(rw*cnt+eps), deR2 = deR^2 ----
__global__ void k_deR(const float* __restrict__ de, const float* __restrict__ rel,
                      float* __restrict__ deR, float* __restrict__ deR2) {
  int i = blockIdx.x * 256 + threadIdx.x;
  int r = i >> 11;
  float rwr = rel_w(rel, r);
  float d = rsqrtf(rwr * de[i] + 1e-8f);
  deR[i] = d;
  deR2[i] = d * d;
}

// ---- f32 [M][C] -> bf16 [R][C][M], row-scaled by dvs[z][m] ----
__global__ void k_cvtTs(const float* __restrict__ src, const float* __restrict__ dvs,
                        unsigned short* __restrict__ dst, int M, int C) {
  __shared__ unsigned short tile[64][65];
  int r = blockIdx.z;
  int c0 = blockIdx.x * 64, m0 = blockIdx.y * 64;
  int tr = threadIdx.x >> 4, tc = threadIdx.x & 15;
#pragma unroll
  for (int i = 0; i < 4; i++) {
    int m = m0 + tr + 16 * i;
    float d = dvs[(size_t)r * M + m];
    float4 v = *(const float4*)(src + (size_t)m * C + c0 + tc * 4);
    tile[tr + 16 * i][tc * 4 + 0] = f2b(v.x * d);
    tile[tr + 16 * i][tc * 4 + 1] = f2b(v.y * d);
    tile[tr + 16 * i][tc * 4 + 2] = f2b(v.z * d);
    tile[tr + 16 * i][tc * 4 + 3] = f2b(v.w * d);
  }
  __syncthreads();
  unsigned short* db = dst + (size_t)r * C * M;
#pragma unroll
  for (int i = 0; i < 4; i++) {
    int c = c0 + tr + 16 * i;
    ushort4 v;
    v.x = tile[tc * 4 + 0][tr + 16 * i];
    v.y = tile[tc * 4 + 1][tr + 16 * i];
    v.z = tile[tc * 4 + 2][tr + 16 * i];
    v.w = tile[tc * 4 + 3][tr + 16 * i];
    *(ushort4*)(db + (size_t)c * M + m0 + tc * 4) = v;
  }
}

// ---- bf16 [M][C] -> bf16 [R][C][M], row-scaled by dvs[z][m] ----
__global__ void k_trzs(const unsigned short* __restrict__ src, const float* __restrict__ dvs,
                       unsigned short* __restrict__ dst, int M, int C) {
  __shared__ unsigned short tile[64][65];
  int r = blockIdx.z;
  int c0 = blockIdx.x * 64, m0 = blockIdx.y * 64;
  int tr = threadIdx.x >> 4, tc = threadIdx.x & 15;
#pragma unroll
  for (int i = 0; i < 4; i++) {
    int m = m0 + tr + 16 * i;
    float d = dvs[(size_t)r * M + m];
    ushort4 v = *(const ushort4*)(src + (size_t)m * C + c0 + tc * 4);
    tile[tr + 16 * i][tc * 4 + 0] = f2b(b2f(v.x) * d);
    tile[tr + 16 * i][tc * 4 + 1] = f2b(b2f(v.y) * d);
    tile[tr + 16 * i][tc * 4 + 2] = f2b(b2f(v.z) * d);
    tile[tr + 16 * i][tc * 4 + 3] = f2b(b2f(v.w) * d);
  }
  __syncthreads();
  unsigned short* db = dst + (size_t)r * C * M;
#pragma unroll
  for (int i = 0; i < 4; i++) {
    int c = c0 + tr + 16 * i;
    ushort4 v;
    v.x = tile[tc * 4 + 0][tr + 16 * i];
    v.y = tile[tc * 4 + 1][tr + 16 * i];
    v.z = tile[tc * 4 + 2][tr + 16 * i];
    v.w = tile[tc * 4 + 3][tr + 16 * i];
    *(ushort4*)(db + (size_t)c * M + m0 + tc * 4) = v;
  }
}

// ---- all three weight transforms in ONE launch ----
__global__ void k_wprep(const float* __restrict__ W1, const float* __restrict__ W2,
                        const float* __restrict__ W3, const float* __restrict__ imp,
                        unsigned short* __restrict__ W1catT, unsigned short* __restrict__ W2T,
                        unsigned short* __restrict__ W3T) {
  int idx = blockIdx.x * 256 + threadIdx.x;
  if (idx < RR * FF * HDD) {
    int o = idx % HDD, f = (idx / HDD) % FF, r = idx / (HDD * FF);
    float sg = 1.0f / (1.0f + expf(-imp[r]));
    W1catT[(size_t)o * (RR * FF) + r * FF + f] = f2b(sg * W1[((size_t)r * FF + f) * HDD + o]);
  } else if (idx < RR * FF * HDD + RR * HDD * HDD) {
    int j = idx - RR * FF * HDD;
    int c = j % HDD, o = (j / HDD) % HDD, r = j / (HDD * HDD);
    float sg = 1.0f / (1.0f + expf(-imp[RR + r]));
    W2T[j] = f2b(sg * W2[((size_t)r * HDD + c) * HDD + o]);
  } else {
    int j = idx - RR * FF * HDD - RR * HDD * HDD;
    int c = j % HDD, o = (j / HDD) % FF, r = j / (HDD * FF);
    float sg = 1.0f / (1.0f + expf(-imp[2 * RR + r]));
    W3T[j] = f2b(sg * W3[((size_t)r * HDD + c) * FF + o]);
  }
}

// ---------------- MFMA GEMM, 128x128 tile, BK=64, async staging (XOR swizzle) ----------------
// DECA/DECB: that operand is a BINARY matrix decoded from a bitmask: zero-fill + sparse
// scatter of 1.0bf16 at set bits (alpha/beta scales are fused outside the GEMM).
// mask row: dm + (zr*drow_rs + rowbase + row)*dnw, bit k of the K-range.
// Optional epilogue column scale: val *= cscale[zr*cs_rs + col].
template <int DECA, int DECB>
__global__ __launch_bounds__(256) void k_gemm3(
    const unsigned short* __restrict__ A, const unsigned short* __restrict__ BT,
    int K, int SK, int lda, int ldb, long a_rs, long b_rs,
    unsigned short* __restrict__ P, long c_ps, long c_rs, int ldc,
    const unsigned long long* __restrict__ dm, int dnw, long drow_rs,
    const float* __restrict__ cscale, long cs_rs) {
  __shared__ unsigned short Al[128 * 64];
  __shared__ unsigned short Bl[128 * 64];
  int tid = threadIdx.x, wid = tid >> 6, lane = tid & 63;
  int m0 = blockIdx.x << 7, n0 = blockIdx.y << 7;
  int z = blockIdx.z, zr = z / SK, kz = z - zr * SK;
  int Kc = K / SK;
  int r8 = lane >> 3, c8 = lane & 7;
  int swz = ((c8 ^ r8) << 3);
  const unsigned short* Ab = A + (DECA ? 0 : ((size_t)zr * a_rs + (size_t)m0 * lda + (size_t)kz * Kc));
  const unsigned short* Bb = BT + (DECB ? 0 : ((size_t)zr * b_rs + (size_t)n0 * ldb + (size_t)kz * Kc));
  // binary-decode setup
  const unsigned int* mrow = nullptr;
  int drow = 0, dhalf = 0, dsw = 0;
  unsigned short* Dl = DECA ? Al : Bl;
  if (DECA || DECB) {
    drow = tid >> 1; dhalf = tid & 1;
    long mrowOff = (long)zr * drow_rs + (DECA ? m0 : n0) + drow;
    mrow = (const unsigned int*)(dm + (size_t)mrowOff * dnw);
    dsw = drow & 7;
  }
  int wm = (wid >> 1) << 6, wn = (wid & 1) << 6;
  int fm = lane & 15, quad = lane >> 4;
  int f7 = fm & 7;
  floatx4 acc[4][4];
#pragma unroll
  for (int i = 0; i < 4; i++)
#pragma unroll
    for (int j = 0; j < 4; j++) acc[i][j] = (floatx4){0.f, 0.f, 0.f, 0.f};
  for (int k0 = 0; k0 < Kc; k0 += 64) {
    if (!DECA) {
#pragma unroll
      for (int t = 0; t < 4; t++) {
        int rbase = (wid << 5) + (t << 3);
        int row = rbase + r8;
        async16(Ab + (size_t)row * lda + k0 + swz, &Al[rbase * 64 + lane * 8]);
      }
    }
    if (!DECB) {
#pragma unroll
      for (int t = 0; t < 4; t++) {
        int rbase = (wid << 5) + (t << 3);
        int row = rbase + r8;
        async16(Bb + (size_t)row * ldb + k0 + swz, &Bl[rbase * 64 + lane * 8]);
      }
    }
    if (DECA || DECB) {
      long kglob = (long)kz * Kc + k0;
      unsigned int bits = mrow[(kglob >> 5) + dhalf];
      uint4 zz = {0u, 0u, 0u, 0u};
#pragma unroll
      for (int g = 0; g < 4; g++) {
        int chunk = ((dhalf << 2) | g) ^ dsw;
        *(uint4*)&Dl[drow * 64 + chunk * 8] = zz;
      }
      while (bits) {
        int b = __builtin_ctz(bits);
        bits &= bits - 1;
        int kl = (dhalf << 5) + b;
        Dl[drow * 64 + (((kl >> 3) ^ dsw) << 3) + (kl & 7)] = (unsigned short)0x3F80;
      }
    }
    __syncthreads();
#pragma unroll
    for (int ks = 0; ks < 2; ks++) {
      int kg = (ks << 2) | quad;
      int ko = ((kg ^ f7) << 3);
      bf16x8 a[4], b[4];
#pragma unroll
      for (int i = 0; i < 4; i++) {
        a[i] = *(const bf16x8*)&Al[(wm + i * 16 + fm) * 64 + ko];
        b[i] = *(const bf16x8*)&Bl[(wn + i * 16 + fm) * 64 + ko];
      }
#pragma unroll
      for (int i = 0; i < 4; i++)
#pragma unroll
        for (int j = 0; j < 4; j++)
          acc[i][j] = __builtin_amdgcn_mfma_f32_16x16x32_bf16(a[i], b[j], acc[i][j], 0, 0, 0);
    }
    __syncthreads();
  }
  unsigned short* Cb = P + (size_t)kz * c_ps + (size_t)zr * c_rs;
  float csc[4];
#pragma unroll
  for (int ni = 0; ni < 4; ni++)
    csc[ni] = cscale ? cscale[(size_t)zr * cs_rs + n0 + wn + ni * 16 + fm] : 1.0f;
#pragma unroll
  for (int mi = 0; mi < 4; mi++)
#pragma unroll
    for (int ni = 0; ni < 4; ni++)
#pragma unroll
      for (int v = 0; v < 4; v++) {
        int row = m0 + wm + mi * 16 + quad * 4 + v;
        int col = n0 + wn + ni * 16 + fm;
        Cb[(size_t)row * ldc + col] = f2b(acc[mi][ni][v] * csc[ni]);
      }
}

// ---- reduce SK bf16 partials per zr -> bf16 out[zr][region], optional index-scale ----
__global__ void k_red_b(const unsigned short* __restrict__ P, unsigned short* __restrict__ out,
                        int SK, long region,
                        const float* __restrict__ sc, long sc_rs, int sc_shift, int sc_mask) {
  long i = ((long)blockIdx.x * 256 + threadIdx.x) * 8;
  int zr = blockIdx.y;
  const unsigned short* p = P + (size_t)zr * SK * region + i;
  float s[8] = {0, 0, 0, 0, 0, 0, 0, 0};
  for (int k = 0; k < SK; k++) {
    const unsigned short* q = p + (size_t)k * region;
    ushort4 a = *(const ushort4*)q;
    ushort4 b = *(const ushort4*)(q + 4);
    s[0] += b2f(a.x); s[1] += b2f(a.y); s[2] += b2f(a.z); s[3] += b2f(a.w);
    s[4] += b2f(b.x); s[5] += b2f(b.y); s[6] += b2f(b.z); s[7] += b2f(b.w);
  }
  float scl[8];
#pragma unroll
  for (int j = 0; j < 8; j++)
    scl[j] = sc ? sc[(size_t)zr * sc_rs + (int)(((i + j) >> sc_shift) & sc_mask)] : 1.0f;
  ushort4 o0, o1;
  o0.x = f2b(s[0] * scl[0]); o0.y = f2b(s[1] * scl[1]); o0.z = f2b(s[2] * scl[2]); o0.w = f2b(s[3] * scl[3]);
  o1.x = f2b(s[4] * scl[4]); o1.y = f2b(s[5] * scl[5]); o1.z = f2b(s[6] * scl[6]); o1.w = f2b(s[7] * scl[7]);
  unsigned short* d = out + (size_t)zr * region + i;
  *(ushort4*)d = o0;
  *(ushort4*)(d + 4) = o1;
}

// ---- reduce SK bf16 partials per r of [NN][FF] -> Hcat[n][r*FF+f] bf16, row-scaled by dvs ----
__global__ void k_red_hcatb(const unsigned short* __restrict__ P, unsigned short* __restrict__ out,
                            int SK, const float* __restrict__ dvs) {
  long i = ((long)blockIdx.x * 256 + threadIdx.x) * 8;
  int r = blockIdx.y;
  const unsigned short* p = P + (size_t)r * SK * (NN * FF) + i;
  float s[8] = {0, 0, 0, 0, 0, 0, 0, 0};
  for (int k = 0; k < SK; k++) {
    const unsigned short* q = p + (size_t)k * (NN * FF);
    ushort4 a = *(const ushort4*)q;
    ushort4 b = *(const ushort4*)(q + 4);
    s[0] += b2f(a.x); s[1] += b2f(a.y); s[2] += b2f(a.z); s[3] += b2f(a.w);
    s[4] += b2f(b.x); s[5] += b2f(b.y); s[6] += b2f(b.z); s[7] += b2f(b.w);
  }
  long n = i >> 7;
  int f = (int)(i & 127);
  float dv = dvs[(size_t)r * NN + n];
  ushort4 o0, o1;
  o0.x = f2b(s[0] * dv); o0.y = f2b(s[1] * dv); o0.z = f2b(s[2] * dv); o0.w = f2b(s[3] * dv);
  o1.x = f2b(s[4] * dv); o1.y = f2b(s[5] * dv); o1.z = f2b(s[6] * dv); o1.w = f2b(s[7] * dv);
  unsigned short* d = out + n * (RR * FF) + r * FF + f;
  *(ushort4*)d = o0;
  *(ushort4*)(d + 4) = o1;
}

// ---- reduce Z bf16 partials of [NN][HDD] -> convout f32 + fused BN stats; per-slot row scale ----
__global__ void k_redstats(const unsigned short* __restrict__ P, float* __restrict__ out,
                           float* __restrict__ cs, float* __restrict__ cs2, int Z,
                           const float* __restrict__ rs, int rshift) {
  __shared__ float sm[2][8][256];
  int cg = (threadIdx.x & 31) << 3;
  int rowt = threadIdx.x >> 5;
  int r0 = blockIdx.x * 32;
  float s[8] = {0, 0, 0, 0, 0, 0, 0, 0}, s2[8] = {0, 0, 0, 0, 0, 0, 0, 0};
  for (int j = 0; j < 4; j++) {
    int row = r0 + rowt * 4 + j;
    long idx = (long)row * HDD + cg;
    float acc[8] = {0, 0, 0, 0, 0, 0, 0, 0};
    for (int z = 0; z < Z; z++) {
      const unsigned short* p = P + (size_t)z * ((long)NN * HDD) + idx;
      float w_ = rs ? rs[(size_t)(z >> rshift) * NN + row] : 1.0f;
      ushort4 a = *(const ushort4*)p;
      ushort4 b = *(const ushort4*)(p + 4);
      acc[0] += b2f(a.x) * w_; acc[1] += b2f(a.y) * w_; acc[2] += b2f(a.z) * w_; acc[3] += b2f(a.w) * w_;
      acc[4] += b2f(b.x) * w_; acc[5] += b2f(b.y) * w_; acc[6] += b2f(b.z) * w_; acc[7] += b2f(b.w) * w_;
    }
    float4 o0 = {acc[0], acc[1], acc[2], acc[3]};
    float4 o1 = {acc[4], acc[5], acc[6], acc[7]};
    *(float4*)(out + idx) = o0;
    *(float4*)(out + idx + 4) = o1;
#pragma unroll
    for (int i = 0; i < 8; i++) { s[i] += acc[i]; s2[i] += acc[i] * acc[i]; }
  }
#pragma unroll
  for (int i = 0; i < 8; i++) { sm[0][rowt][cg + i] = s[i]; sm[1][rowt][cg + i] = s2[i]; }
  __syncthreads();
  int c = threadIdx.x;
  float a0 = 0, a1 = 0;
#pragma unroll
  for (int t = 0; t < 8; t++) { a0 += sm[0][t][c]; a1 += sm[1][t][c]; }
  atomicAdd(&cs[c], a0);
  atomicAdd(&cs2[c], a1);
}

// ---- final: d_out = X + b3 + sum_Z dv-scaled bf16 partials [Z][NN][FF] ----
__global__ void k_red_out(const unsigned short* __restrict__ P, const float* __restrict__ X,
                          const float* __restrict__ b3, float* __restrict__ out, int Z,
                          const float* __restrict__ rs) {
  long i = ((long)blockIdx.x * 256 + threadIdx.x) * 4;
  long n = i >> 7;
  int f = (int)(i & 127);
  float4 s = *(const float4*)(X + i);
  s.x += b3[f]; s.y += b3[f + 1]; s.z += b3[f + 2]; s.w += b3[f + 3];
  for (int z = 0; z < Z; z++) {
    float w_ = rs[(size_t)(z >> 1) * NN + n];
    ushort4 v = *(const ushort4*)(P + (size_t)z * (NN * FF) + i);
    s.x += b2f(v.x) * w_; s.y += b2f(v.y) * w_; s.z += b2f(v.z) * w_; s.w += b2f(v.w) * w_;
  }
  *(float4*)(out + i) = s;
}

// ---- BN (batch stats) -> LN -> ELU -> bf16 [NN][HDD] ----
__global__ void k_bnlnelu(const float* __restrict__ x, const float* __restrict__ cs, const float* __restrict__ cs2,
                          const float* __restrict__ bg, const float* __restrict__ bb,
                          const float* __restrict__ lg, const float* __restrict__ lb,
                          unsigned short* __restrict__ out) {
  int wid = threadIdx.x >> 6, lane = threadIdx.x & 63;
  int n = blockIdx.x * 4 + wid;
  float y[4];
  float m = 0.f;
#pragma unroll
  for (int j = 0; j < 4; j++) {
    int c = lane + 64 * j;
    float mu = cs[c] * (1.0f / NN);
    float var = cs2[c] * (1.0f / NN) - mu * mu;
    float xv = x[(size_t)n * HDD + c];
    y[j] = (xv - mu) * rsqrtf(var + 1e-5f) * bg[c] + bb[c];
    m += y[j];
  }
  for (int off = 32; off; off >>= 1) m += __shfl_down(m, off);
  m = __shfl(m, 0) * (1.0f / HDD);
  float var = 0.f;
#pragma unroll
  for (int j = 0; j < 4; j++) { float d = y[j] - m; var += d * d; }
  for (int off = 32; off; off >>= 1) var += __shfl_down(var, off);
  var = __shfl(var, 0) * (1.0f / HDD);
  float inv = rsqrtf(var + 1e-5f);
#pragma unroll
  for (int j = 0; j < 4; j++) {
    int c = lane + 64 * j;
    float z = (y[j] - m) * inv * lg[c] + lb[c];
    z = z > 0.f ? z : expm1f(z);
    out[(size_t)n * HDD + c] = f2b(z);
  }
}

extern "C" void kernel_launch(void* const* d_in, const int* in_sizes, int n_in,
                              void* d_out, int out_size, void* d_ws, size_t ws_size,
                              hipStream_t stream) {
  const float* X   = (const float*)d_in[0];
  const float* H   = (const float*)d_in[1];
  const float* W1  = (const float*)d_in[2];
  const float* W2  = (const float*)d_in[3];
  const float* W3  = (const float*)d_in[4];
  const float* imp = (const float*)d_in[5];
  const float* b3  = (const float*)d_in[8];
  const float* bng = (const float*)d_in[9];
  const float* bnb = (const float*)d_in[10];
  const float* lng = (const float*)d_in[11];
  const float* lnb = (const float*)d_in[12];
  const float* rel = (const float*)d_in[13];
  (void)in_sizes; (void)n_in; (void)out_size; (void)ws_size;

  char* w = (char*)d_ws;
  size_t off = 0;
  auto alloc = [&](size_t bytes) -> void* {
    void* p = w + off;
    off += (bytes + 255) & ~(size_t)255;
    return p;
  };
  float* dvs  = (float*)alloc((size_t)RR * NN * 4);
  float* de   = (float*)alloc((size_t)RR * EE * 4);
  float* deR  = (float*)alloc((size_t)RR * EE * 4);
  float* deR2 = (float*)alloc((size_t)RR * EE * 4);
  float* cs   = (float*)alloc(2 * HDD * 4);
  unsigned long long* mask1 = (unsigned long long*)alloc((size_t)RR * NN * (EE / 64) * 8);  // 4MB
  unsigned long long* mask2 = (unsigned long long*)alloc((size_t)RR * EE * (NN / 64) * 8);  // 4MB
  unsigned short* bufP = (unsigned short*)alloc((size_t)16 * NN * HDD * 2);    // 32MB bf16 partials
  unsigned short* bufC = (unsigned short*)alloc((size_t)RR * EE * HDD * 2);    // 4MB
  unsigned short* bufD = (unsigned short*)alloc((size_t)RR * EE * HDD * 2);    // 4MB
  unsigned short* bufE = (unsigned short*)alloc((size_t)RR * EE * HDD * 2);    // 4MB
  float* convout = (float*)alloc((size_t)NN * HDD * 4);                        // 4MB
  unsigned short* Xb   = (unsigned short*)alloc((size_t)NN * HDD * 2);         // 2MB
  unsigned short* XdvT = (unsigned short*)alloc((size_t)RR * FF * NN * 2);     // 4MB
  unsigned short* hdvT = (unsigned short*)alloc((size_t)RR * HDD * NN * 2);    // 8MB
  unsigned short* W1catT = (unsigned short*)alloc((size_t)RR * FF * HDD * 2);
  unsigned short* W2T    = (unsigned short*)alloc((size_t)RR * HDD * HDD * 2);
  unsigned short* W3T    = (unsigned short*)alloc((size_t)RR * HDD * FF * 2);

  // ---- prep ----
  k_dvmask<<<(RR * NN) / 4, 256, 0, stream>>>(H, rel, dvs, mask1);
  hipMemsetAsync(de, 0, (size_t)RR * EE * 4, stream);
  k_maskT<<<RR * (NN / 64), 256, 0, stream>>>(mask1, mask2, de);
  k_deR<<<(RR * EE) / 256, 256, 0, stream>>>(de, rel, deR, deR2);
  k_cvtTs<<<dim3(FF / 64, NN / 64, RR), 256, 0, stream>>>(X, dvs, XdvT, NN, FF);  // XdvT[r][f][n]
  k_wprep<<<(RR * FF * HDD + RR * HDD * HDD + RR * HDD * FF) / 256, 256, 0, stream>>>(
      W1, W2, W3, imp, W1catT, W2T, W3T);

  // ---- layer 1 (128 -> 256) ----
  // raw1T[r][f][e] = sum_n XdvT[r][f][n] B2[e][n]   M=128,N=2048,K=4096, z=(r,SK8)
  k_gemm3<0, 1><<<dim3(1, EE / 128, RR * 8), 256, 0, stream>>>(
      XdvT, nullptr, NN, 8, NN, 0, (long)FF * NN, 0,
      bufP, (long)FF * EE, 8L * FF * EE, EE, mask2, NN / 64, EE, nullptr, 0);
  // bufC = de^2 * raw1T  (theta de from conv-in + de pre-scale for next GEMM)
  k_red_b<<<dim3((FF * EE) / 2048, RR), 256, 0, stream>>>(
      bufP, bufC, 8, (long)FF * EE, deR2, EE, 0, EE - 1);
  // Hcat_raw[n][f] = sum_e B1[n][e] bufC[r][f][e]   M=4096,N=128,K=2048, z=(r,SK2)
  k_gemm3<1, 0><<<dim3(NN / 128, 1, RR * 2), 256, 0, stream>>>(
      nullptr, bufC, EE, 2, 0, EE, 0, (long)FF * EE,
      bufP, (long)NN * FF, 2L * NN * FF, FF, mask1, EE / 64, NN, nullptr, 0);
  k_red_hcatb<<<dim3((NN * FF) / 2048, RR), 256, 0, stream>>>(bufP, bufD, 2, dvs);  // Hcatb [4096][512]
  // convout = Hcatb @ W1cat   M=4096,N=256,K=512, SK=4 (b1 dropped: BN-invariant)
  k_gemm3<0, 0><<<dim3(NN / 128, HDD / 128, 4), 256, 0, stream>>>(
      bufD, W1catT, RR * FF, 4, RR * FF, RR * FF, 0, 0,
      bufP, (long)NN * HDD, 0, HDD, nullptr, 0, 0, nullptr, 0);
  hipMemsetAsync(cs, 0, 2 * HDD * 4, stream);
  k_redstats<<<NN / 32, 256, 0, stream>>>(bufP, convout, cs, cs + HDD, 4, nullptr, 0);
  k_bnlnelu<<<NN / 4, 256, 0, stream>>>(convout, cs, cs + HDD, bng, bnb, lng, lnb, Xb);
  k_trzs<<<dim3(HDD / 64, NN / 64, RR), 256, 0, stream>>>(Xb, dvs, hdvT, NN, HDD);  // hdvT[r][c][n]

  // ---- layer 2 (256 -> 256) ----
  // raw2[r][e][c] = sum_n B2[e][n] hdvT[r][c][n]   per-r M=2048,N=256,K=4096, z=(r,SK4)
  k_gemm3<1, 0><<<dim3(EE / 128, HDD / 128, RR * 4), 256, 0, stream>>>(
      nullptr, hdvT, NN, 4, 0, NN, 0, (long)HDD * NN,
      bufP, (long)RR * EE * HDD, (long)EE * HDD, HDD, mask2, NN / 64, EE, nullptr, 0);
  // bufD = de * raw2 = true t2
  k_red_b<<<dim3((RR * EE * HDD) / 2048, 1), 256, 0, stream>>>(
      bufP, bufD, 4, (long)RR * EE * HDD, deR, 0, 8, RR * EE - 1);
  // uT[r][o][e] = sum_c W2T[r][o][c] t2[r][e][c], epilogue * de[e]   M=256,N=2048,K=256, z=r
  k_gemm3<0, 0><<<dim3(HDD / 128, EE / 128, RR), 256, 0, stream>>>(
      W2T, bufD, HDD, 1, HDD, HDD, (long)HDD * HDD, (long)EE * HDD,
      bufE, 0, (long)HDD * EE, EE, nullptr, 0, 0, deR, EE);
  // raw_out[n][o] = sum_e B1[n][e] bufE[r][o][e]   M=4096,N=256,K=2048, z=(r,SK2)
  k_gemm3<1, 0><<<dim3(NN / 128, HDD / 128, RR * 2), 256, 0, stream>>>(
      nullptr, bufE, EE, 2, 0, EE, 0, (long)HDD * EE,
      bufP, (long)NN * HDD, 2L * NN * HDD, HDD, mask1, EE / 64, NN, nullptr, 0);
  hipMemsetAsync(cs, 0, 2 * HDD * 4, stream);
  k_redstats<<<NN / 32, 256, 0, stream>>>(bufP, convout, cs, cs + HDD, 8, dvs, 1);
  k_bnlnelu<<<NN / 4, 256, 0, stream>>>(convout, cs, cs + HDD, bng + HDD, bnb + HDD, lng + HDD, lnb + HDD, Xb);

  // ---- layer 3 (256 -> 128), W3 applied first ----
  // ydvT[r][f][n] = (sum_c W3T[r][f][c] Xb[n][c]) * dv[r][n]   M=128,N=4096,K=256, z=r
  k_gemm3<0, 0><<<dim3(1, NN / 128, RR), 256, 0, stream>>>(
      W3T, Xb, HDD, 1, HDD, HDD, (long)FF * HDD, 0,
      bufD, 0, (long)FF * NN, NN, nullptr, 0, 0, dvs, NN);
  // raw3[r][f][e] = sum_n ydvT[r][f][n] B2[e][n]   M=128,N=2048,K=4096, z=(r,SK8)
  k_gemm3<0, 1><<<dim3(1, EE / 128, RR * 8), 256, 0, stream>>>(
      bufD, nullptr, NN, 8, NN, 0, (long)FF * NN, 0,
      bufP, (long)FF * EE, 8L * FF * EE, EE, mask2, NN / 64, EE, nullptr, 0);
  // bufC = de^2 * raw3
  k_red_b<<<dim3((FF * EE) / 2048, RR), 256, 0, stream>>>(
      bufP, bufC, 8, (long)FF * EE, deR2, EE, 0, EE - 1);
  // P[z] = B1[r] @ bufC[r]   M=4096,N=128,K=2048, z=(r,SK2)
  k_gemm3<1, 0><<<dim3(NN / 128, 1, RR * 2), 256, 0, stream>>>(
      nullptr, bufC, EE, 2, 0, EE, 0, (long)FF * EE,
      bufP, (long)NN * FF, 2L * NN * FF, FF, mask1, EE / 64, NN, nullptr, 0);
  // d_out = X + b3 + sum_z dv[r][n] * P[z]
  k_red_out<<<(NN * FF) / 1024, 256, 0, stream>>>(bufP, X, b3, (float*)d_out, 8, dvs);
}

// Round 4
// 470.073 us; speedup vs baseline: 1.2709x; 1.0454x over previous
//
#include <hip/hip_runtime.h>
#include <hip/hip_bf16.h>

#define NN 4096
#define EE 2048
#define RR 4
#define FF 128
#define HDD 256

typedef __attribute__((ext_vector_type(4))) float floatx4;
typedef __attribute__((ext_vector_type(8))) __bf16 bf16x8;

#define AS1 __attribute__((address_space(1)))
#define AS3 __attribute__((address_space(3)))

__device__ __forceinline__ void async16(const void* g, void* l) {
  __builtin_amdgcn_global_load_lds((const AS1 void*)(unsigned long long)(g),
                                   (AS3 void*)(unsigned int)(unsigned long long)(l),
                                   16, 0, 0);
}

__device__ inline unsigned short f2b(float x) {
  unsigned int u = __float_as_uint(x);
  unsigned int r = u + 0x7fffu + ((u >> 16) & 1u);
  return (unsigned short)(r >> 16);
}
__device__ inline float b2f(unsigned short u) { return __uint_as_float((unsigned int)u << 16); }

__device__ inline float rel_w(const float* rel, int r) {
  float m = fmaxf(fmaxf(rel[0], rel[1]), fmaxf(rel[2], rel[3]));
  float s = 0.f;
#pragma unroll
  for (int i = 0; i < RR; i++) s += expf(rel[i] - m);
  return expf(rel[r] - m) / s;
}

// ==== prep1: fused {dvmask | wprep | zero(de,cs)} by block range ====
// dvmask: single pass over H: row sums -> dvs[r][n], plus mask1[r][n][e/64] (bit l of word j <-> e=j*64+l)
__global__ void k_prep1(const float* __restrict__ H, const float* __restrict__ rel,
                        const float* __restrict__ W1, const float* __restrict__ W2,
                        const float* __restrict__ W3, const float* __restrict__ imp,
                        float* __restrict__ dvs, unsigned long long* __restrict__ mask,
                        unsigned short* __restrict__ W1catT, unsigned short* __restrict__ W2T,
                        unsigned short* __restrict__ W3T, float* __restrict__ de, float* __restrict__ cs) {
  int b = blockIdx.x;
  if (b < 4096) {
    int wave = (b << 2) | (threadIdx.x >> 6);  // = r*NN + n
    int lane = threadIdx.x & 63;
    int r = wave >> 12;
    const float* row = H + (size_t)wave * EE;
    unsigned long long* mrow = mask + (size_t)wave * (EE / 64);
    float s = 0.f;
    for (int j = 0; j < EE / 64; j++) {
      float h = row[j * 64 + lane];
      s += h;
      unsigned long long m = __ballot(h != 0.0f);
      if (lane == 0) mrow[j] = m;
    }
    for (int off = 32; off; off >>= 1) s += __shfl_down(s, off);
    if (lane == 0) {
      float rwr = rel_w(rel, r);
      dvs[wave] = rwr * rsqrtf(rwr * s + 1e-8f);
    }
  } else if (b < 4096 + 2048) {
    int idx = (b - 4096) * 256 + threadIdx.x;
    if (idx < RR * FF * HDD) {
      int o = idx % HDD, f = (idx / HDD) % FF, r = idx / (HDD * FF);
      float sg = 1.0f / (1.0f + expf(-imp[r]));
      W1catT[(size_t)o * (RR * FF) + r * FF + f] = f2b(sg * W1[((size_t)r * FF + f) * HDD + o]);
    } else if (idx < RR * FF * HDD + RR * HDD * HDD) {
      int j = idx - RR * FF * HDD;
      int c = j % HDD, o = (j / HDD) % HDD, r = j / (HDD * HDD);
      float sg = 1.0f / (1.0f + expf(-imp[RR + r]));
      W2T[j] = f2b(sg * W2[((size_t)r * HDD + c) * HDD + o]);
    } else {
      int j = idx - RR * FF * HDD - RR * HDD * HDD;
      int c = j % HDD, o = (j / HDD) % FF, r = j / (HDD * FF);
      float sg = 1.0f / (1.0f + expf(-imp[2 * RR + r]));
      W3T[j] = f2b(sg * W3[((size_t)r * HDD + c) * FF + o]);
    }
  } else {
    int i = (b - 6144) * 256 + threadIdx.x;
    if (i < RR * EE) de[i] = 0.f;
    else if (i < RR * EE + 2 * HDD) cs[i - RR * EE] = 0.f;
  }
}

// ==== prep2: fused {maskT (bit-transpose + de counts) | cvtTs (X -> dv-scaled bf16 [r][f][n])} ====
__global__ void k_prep2(const unsigned long long* __restrict__ m1, unsigned long long* __restrict__ m2,
                        float* __restrict__ de, const float* __restrict__ X,
                        const float* __restrict__ dvs, unsigned short* __restrict__ XdvT) {
  __shared__ unsigned long long w[64 * 33];
  __shared__ unsigned short tile[64][65];
  int t = threadIdx.x;
  if (blockIdx.x < 256) {
    int r = blockIdx.x >> 6;
    int n0 = (blockIdx.x & 63) << 6;
    const unsigned long long* src = m1 + ((size_t)r * NN + n0) * 32;
#pragma unroll
    for (int i = 0; i < 8; i++) {
      int idx = t + i * 256;
      int n = idx >> 5, W = idx & 31;
      w[n * 33 + W] = src[idx];
    }
    __syncthreads();
    int wid = t >> 6, lane = t & 63;
    int v = n0 >> 6;
#pragma unroll
    for (int Wi = 0; Wi < 8; Wi++) {
      int W = wid * 8 + Wi;
      unsigned long long myw = w[lane * 33 + W];
      unsigned long long out = 0;
      for (int b = 0; b < 64; b++) {
        unsigned long long mm = __ballot(((myw >> b) & 1ULL) != 0);
        if (lane == b) out = mm;
      }
      m2[((size_t)r * EE + W * 64 + lane) * 64 + v] = out;
      atomicAdd(&de[r * EE + W * 64 + lane], (float)__popcll(out));
    }
  } else {
    int idx = blockIdx.x - 256;
    int c0 = (idx & 1) * 64, m0 = ((idx >> 1) & 63) * 64, r = idx >> 7;
    int tr = t >> 4, tc = t & 15;
#pragma unroll
    for (int i = 0; i < 4; i++) {
      int m = m0 + tr + 16 * i;
      float d = dvs[(size_t)r * NN + m];
      float4 v = *(const float4*)(X + (size_t)m * FF + c0 + tc * 4);
      tile[tr + 16 * i][tc * 4 + 0] = f2b(v.x * d);
      tile[tr + 16 * i][tc * 4 + 1] = f2b(v.y * d);
      tile[tr + 16 * i][tc * 4 + 2] = f2b(v.z * d);
      tile[tr + 16 * i][tc * 4 + 3] = f2b(v.w * d);
    }
    __syncthreads();
    unsigned short* db = XdvT + (size_t)r * FF * NN;
#pragma unroll
    for (int i = 0; i < 4; i++) {
      int c = c0 + tr + 16 * i;
      ushort4 v;
      v.x = tile[tc * 4 + 0][tr + 16 * i];
      v.y = tile[tc * 4 + 1][tr + 16 * i];
      v.z = tile[tc * 4 + 2][tr + 16 * i];
      v.w = tile[tc * 4 + 3][tr + 16 * i];
      *(ushort4*)(db + (size_t)c * NN + m0 + tc * 4) = v;
    }
  }
}

// ---------------- MFMA GEMM, 128x128 tile, BK=64, single-barrier double-buffered pipeline ----------------
// DECA/DECB: that operand decoded from a bitmask as BINARY (zero-fill + scatter 1.0bf16).
// Schedule per k-step: stage(next buf) -> compute(cur buf) -> one __syncthreads (drain lands after compute).
// z = zr*SK + kz. Partial C at P + kz*c_ps + zr*c_rs. Optional epilogue col scale cscale[zr*cs_rs+col].
template <int DECA, int DECB>
__global__ __launch_bounds__(256) void k_gemm3(
    const unsigned short* __restrict__ A, const unsigned short* __restrict__ BT,
    int K, int SK, int lda, int ldb, long a_rs, long b_rs,
    unsigned short* __restrict__ P, long c_ps, long c_rs, int ldc,
    const unsigned long long* __restrict__ dm, int dnw, long drow_rs,
    const float* __restrict__ cscale, long cs_rs) {
  __shared__ unsigned short Al[2][128 * 64];
  __shared__ unsigned short Bl[2][128 * 64];
  int tid = threadIdx.x, wid = tid >> 6, lane = tid & 63;
  int m0 = blockIdx.x << 7, n0 = blockIdx.y << 7;
  int z = blockIdx.z, zr = z / SK, kz = z - zr * SK;
  int Kc = K / SK;
  int r8 = lane >> 3, c8 = lane & 7;
  int swz = ((c8 ^ r8) << 3);
  const unsigned short* Ab = A + (DECA ? 0 : ((size_t)zr * a_rs + (size_t)m0 * lda + (size_t)kz * Kc));
  const unsigned short* Bb = BT + (DECB ? 0 : ((size_t)zr * b_rs + (size_t)n0 * ldb + (size_t)kz * Kc));
  const unsigned int* mrow = nullptr;
  int drow = 0, dhalf = 0, dsw = 0;
  if (DECA || DECB) {
    drow = tid >> 1; dhalf = tid & 1;
    long mrowOff = (long)zr * drow_rs + (DECA ? m0 : n0) + drow;
    mrow = (const unsigned int*)(dm + (size_t)mrowOff * dnw);
    dsw = drow & 7;
  }
  auto stage = [&](int pb, int k0) {
    if (!DECA) {
#pragma unroll
      for (int t = 0; t < 4; t++) {
        int rbase = (wid << 5) + (t << 3);
        int row = rbase + r8;
        async16(Ab + (size_t)row * lda + k0 + swz, &Al[pb][rbase * 64 + lane * 8]);
      }
    }
    if (!DECB) {
#pragma unroll
      for (int t = 0; t < 4; t++) {
        int rbase = (wid << 5) + (t << 3);
        int row = rbase + r8;
        async16(Bb + (size_t)row * ldb + k0 + swz, &Bl[pb][rbase * 64 + lane * 8]);
      }
    }
    if (DECA || DECB) {
      unsigned short* Dl = DECA ? &Al[pb][0] : &Bl[pb][0];
      long kglob = (long)kz * Kc + k0;
      unsigned int bits = mrow[(kglob >> 5) + dhalf];
      uint4 zz = {0u, 0u, 0u, 0u};
#pragma unroll
      for (int g = 0; g < 4; g++) {
        int chunk = ((dhalf << 2) | g) ^ dsw;
        *(uint4*)&Dl[drow * 64 + chunk * 8] = zz;
      }
      while (bits) {
        int b = __builtin_ctz(bits);
        bits &= bits - 1;
        int kl = (dhalf << 5) + b;
        Dl[drow * 64 + (((kl >> 3) ^ dsw) << 3) + (kl & 7)] = (unsigned short)0x3F80;
      }
    }
  };
  int wm = (wid >> 1) << 6, wn = (wid & 1) << 6;
  int fm = lane & 15, quad = lane >> 4;
  int f7 = fm & 7;
  floatx4 acc[4][4];
#pragma unroll
  for (int i = 0; i < 4; i++)
#pragma unroll
    for (int j = 0; j < 4; j++) acc[i][j] = (floatx4){0.f, 0.f, 0.f, 0.f};
  auto compute = [&](int pb) {
#pragma unroll
    for (int ks = 0; ks < 2; ks++) {
      int kg = (ks << 2) | quad;
      int ko = ((kg ^ f7) << 3);
      bf16x8 a[4], b[4];
#pragma unroll
      for (int i = 0; i < 4; i++) {
        a[i] = *(const bf16x8*)&Al[pb][(wm + i * 16 + fm) * 64 + ko];
        b[i] = *(const bf16x8*)&Bl[pb][(wn + i * 16 + fm) * 64 + ko];
      }
#pragma unroll
      for (int i = 0; i < 4; i++)
#pragma unroll
        for (int j = 0; j < 4; j++)
          acc[i][j] = __builtin_amdgcn_mfma_f32_16x16x32_bf16(a[i], b[j], acc[i][j], 0, 0, 0);
    }
  };
  stage(0, 0);
  __syncthreads();
  for (int k0 = 0; k0 < Kc; k0 += 128) {   // all callers have Kc % 128 == 0
    if (k0 + 64 < Kc) stage(1, k0 + 64);
    compute(0);
    __syncthreads();
    if (k0 + 128 < Kc) stage(0, k0 + 128);
    compute(1);
    __syncthreads();
  }
  unsigned short* Cb = P + (size_t)kz * c_ps + (size_t)zr * c_rs;
  float csc[4];
#pragma unroll
  for (int ni = 0; ni < 4; ni++)
    csc[ni] = cscale ? cscale[(size_t)zr * cs_rs + n0 + wn + ni * 16 + fm] : 1.0f;
#pragma unroll
  for (int mi = 0; mi < 4; mi++)
#pragma unroll
    for (int ni = 0; ni < 4; ni++)
#pragma unroll
      for (int v = 0; v < 4; v++) {
        int row = m0 + wm + mi * 16 + quad * 4 + v;
        int col = n0 + wn + ni * 16 + fm;
        Cb[(size_t)row * ldc + col] = f2b(acc[mi][ni][v] * csc[ni]);
      }
}

// ---- reduce SK bf16 partials per zr(=r) -> bf16 out[zr][region], scaled by de^-2 over e=i%EE ----
__global__ void k_red_b(const unsigned short* __restrict__ P, unsigned short* __restrict__ out,
                        int SK, long region, const float* __restrict__ de,
                        const float* __restrict__ rel, float* __restrict__ cszero) {
  if (cszero && blockIdx.x == 0 && blockIdx.y == 0) {
    cszero[threadIdx.x] = 0.f;
    cszero[threadIdx.x + 256] = 0.f;
  }
  long i = ((long)blockIdx.x * 256 + threadIdx.x) * 8;
  int zr = blockIdx.y;
  const unsigned short* p = P + (size_t)zr * SK * region + i;
  float s[8] = {0, 0, 0, 0, 0, 0, 0, 0};
  for (int k = 0; k < SK; k++) {
    const unsigned short* q = p + (size_t)k * region;
    ushort4 a = *(const ushort4*)q;
    ushort4 b = *(const ushort4*)(q + 4);
    s[0] += b2f(a.x); s[1] += b2f(a.y); s[2] += b2f(a.z); s[3] += b2f(a.w);
    s[4] += b2f(b.x); s[5] += b2f(b.y); s[6] += b2f(b.z); s[7] += b2f(b.w);
  }
  float rwr = rel_w(rel, zr);
  int e0 = (int)(i & (EE - 1));
  float scl[8];
#pragma unroll
  for (int j = 0; j < 8; j++) scl[j] = 1.0f / (rwr * de[zr * EE + e0 + j] + 1e-8f);
  ushort4 o0, o1;
  o0.x = f2b(s[0] * scl[0]); o0.y = f2b(s[1] * scl[1]); o0.z = f2b(s[2] * scl[2]); o0.w = f2b(s[3] * scl[3]);
  o1.x = f2b(s[4] * scl[4]); o1.y = f2b(s[5] * scl[5]); o1.z = f2b(s[6] * scl[6]); o1.w = f2b(s[7] * scl[7]);
  unsigned short* d = out + (size_t)zr * region + i;
  *(ushort4*)d = o0;
  *(ushort4*)(d + 4) = o1;
}

// ---- reduce SK bf16 partials per r of [NN][FF] -> Hcat[n][r*FF+f] bf16, row-scaled by dvs ----
__global__ void k_red_hcatb(const unsigned short* __restrict__ P, unsigned short* __restrict__ out,
                            int SK, const float* __restrict__ dvs) {
  long i = ((long)blockIdx.x * 256 + threadIdx.x) * 8;
  int r = blockIdx.y;
  const unsigned short* p = P + (size_t)r * SK * (NN * FF) + i;
  float s[8] = {0, 0, 0, 0, 0, 0, 0, 0};
  for (int k = 0; k < SK; k++) {
    const unsigned short* q = p + (size_t)k * (NN * FF);
    ushort4 a = *(const ushort4*)q;
    ushort4 b = *(const ushort4*)(q + 4);
    s[0] += b2f(a.x); s[1] += b2f(a.y); s[2] += b2f(a.z); s[3] += b2f(a.w);
    s[4] += b2f(b.x); s[5] += b2f(b.y); s[6] += b2f(b.z); s[7] += b2f(b.w);
  }
  long n = i >> 7;
  int f = (int)(i & 127);
  float dv = dvs[(size_t)r * NN + n];
  ushort4 o0, o1;
  o0.x = f2b(s[0] * dv); o0.y = f2b(s[1] * dv); o0.z = f2b(s[2] * dv); o0.w = f2b(s[3] * dv);
  o1.x = f2b(s[4] * dv); o1.y = f2b(s[5] * dv); o1.z = f2b(s[6] * dv); o1.w = f2b(s[7] * dv);
  unsigned short* d = out + n * (RR * FF) + r * FF + f;
  *(ushort4*)d = o0;
  *(ushort4*)(d + 4) = o1;
}

// ---- reduce Z bf16 partials of [NN][HDD] -> convout f32 + fused BN stats; per-slot row scale ----
__global__ void k_redstats(const unsigned short* __restrict__ P, float* __restrict__ out,
                           float* __restrict__ cs, float* __restrict__ cs2, int Z,
                           const float* __restrict__ rs, int rshift) {
  __shared__ float sm[2][8][256];
  int cg = (threadIdx.x & 31) << 3;
  int rowt = threadIdx.x >> 5;
  int r0 = blockIdx.x * 32;
  float s[8] = {0, 0, 0, 0, 0, 0, 0, 0}, s2[8] = {0, 0, 0, 0, 0, 0, 0, 0};
  for (int j = 0; j < 4; j++) {
    int row = r0 + rowt * 4 + j;
    long idx = (long)row * HDD + cg;
    float acc[8] = {0, 0, 0, 0, 0, 0, 0, 0};
    for (int z = 0; z < Z; z++) {
      const unsigned short* p = P + (size_t)z * ((long)NN * HDD) + idx;
      float w_ = rs ? rs[(size_t)(z >> rshift) * NN + row] : 1.0f;
      ushort4 a = *(const ushort4*)p;
      ushort4 b = *(const ushort4*)(p + 4);
      acc[0] += b2f(a.x) * w_; acc[1] += b2f(a.y) * w_; acc[2] += b2f(a.z) * w_; acc[3] += b2f(a.w) * w_;
      acc[4] += b2f(b.x) * w_; acc[5] += b2f(b.y) * w_; acc[6] += b2f(b.z) * w_; acc[7] += b2f(b.w) * w_;
    }
    float4 o0 = {acc[0], acc[1], acc[2], acc[3]};
    float4 o1 = {acc[4], acc[5], acc[6], acc[7]};
    *(float4*)(out + idx) = o0;
    *(float4*)(out + idx + 4) = o1;
#pragma unroll
    for (int i = 0; i < 8; i++) { s[i] += acc[i]; s2[i] += acc[i] * acc[i]; }
  }
#pragma unroll
  for (int i = 0; i < 8; i++) { sm[0][rowt][cg + i] = s[i]; sm[1][rowt][cg + i] = s2[i]; }
  __syncthreads();
  int c = threadIdx.x;
  float a0 = 0, a1 = 0;
#pragma unroll
  for (int t = 0; t < 8; t++) { a0 += sm[0][t][c]; a1 += sm[1][t][c]; }
  atomicAdd(&cs[c], a0);
  atomicAdd(&cs2[c], a1);
}

// ---- final: d_out = X + b3 + sum_Z dv-scaled bf16 partials [Z][NN][FF] ----
__global__ void k_red_out(const unsigned short* __restrict__ P, const float* __restrict__ X,
                          const float* __restrict__ b3, float* __restrict__ out, int Z,
                          const float* __restrict__ rs) {
  long i = ((long)blockIdx.x * 256 + threadIdx.x) * 4;
  long n = i >> 7;
  int f = (int)(i & 127);
  float4 s = *(const float4*)(X + i);
  s.x += b3[f]; s.y += b3[f + 1]; s.z += b3[f + 2]; s.w += b3[f + 3];
  for (int z = 0; z < Z; z++) {
    float w_ = rs[(size_t)(z >> 1) * NN + n];
    ushort4 v = *(const ushort4*)(P + (size_t)z * (NN * FF) + i);
    s.x += b2f(v.x) * w_; s.y += b2f(v.y) * w_; s.z += b2f(v.z) * w_; s.w += b2f(v.w) * w_;
  }
  *(float4*)(out + i) = s;
}

// ---- BN (batch stats) -> LN -> ELU -> bf16 [NN][HDD] ----
__global__ void k_bnlnelu(const float* __restrict__ x, const float* __restrict__ cs, const float* __restrict__ cs2,
                          const float* __restrict__ bg, const float* __restrict__ bb,
                          const float* __restrict__ lg, const float* __restrict__ lb,
                          unsigned short* __restrict__ out) {
  int wid = threadIdx.x >> 6, lane = threadIdx.x & 63;
  int n = blockIdx.x * 4 + wid;
  float y[4];
  float m = 0.f;
#pragma unroll
  for (int j = 0; j < 4; j++) {
    int c = lane + 64 * j;
    float mu = cs[c] * (1.0f / NN);
    float var = cs2[c] * (1.0f / NN) - mu * mu;
    float xv = x[(size_t)n * HDD + c];
    y[j] = (xv - mu) * rsqrtf(var + 1e-5f) * bg[c] + bb[c];
    m += y[j];
  }
  for (int off = 32; off; off >>= 1) m += __shfl_down(m, off);
  m = __shfl(m, 0) * (1.0f / HDD);
  float var = 0.f;
#pragma unroll
  for (int j = 0; j < 4; j++) { float d = y[j] - m; var += d * d; }
  for (int off = 32; off; off >>= 1) var += __shfl_down(var, off);
  var = __shfl(var, 0) * (1.0f / HDD);
  float inv = rsqrtf(var + 1e-5f);
#pragma unroll
  for (int j = 0; j < 4; j++) {
    int c = lane + 64 * j;
    float z = (y[j] - m) * inv * lg[c] + lb[c];
    z = z > 0.f ? z : expm1f(z);
    out[(size_t)n * HDD + c] = f2b(z);
  }
}

extern "C" void kernel_launch(void* const* d_in, const int* in_sizes, int n_in,
                              void* d_out, int out_size, void* d_ws, size_t ws_size,
                              hipStream_t stream) {
  const float* X   = (const float*)d_in[0];
  const float* H   = (const float*)d_in[1];
  const float* W1  = (const float*)d_in[2];
  const float* W2  = (const float*)d_in[3];
  const float* W3  = (const float*)d_in[4];
  const float* imp = (const float*)d_in[5];
  const float* b3  = (const float*)d_in[8];
  const float* bng = (const float*)d_in[9];
  const float* bnb = (const float*)d_in[10];
  const float* lng = (const float*)d_in[11];
  const float* lnb = (const float*)d_in[12];
  const float* rel = (const float*)d_in[13];
  (void)in_sizes; (void)n_in; (void)out_size; (void)ws_size;

  char* w = (char*)d_ws;
  size_t off = 0;
  auto alloc = [&](size_t bytes) -> void* {
    void* p = w + off;
    off += (bytes + 255) & ~(size_t)255;
    return p;
  };
  float* dvs  = (float*)alloc((size_t)RR * NN * 4);
  float* de   = (float*)alloc((size_t)RR * EE * 4);
  float* cs   = (float*)alloc(2 * HDD * 4);
  unsigned long long* mask1 = (unsigned long long*)alloc((size_t)RR * NN * (EE / 64) * 8);  // 4MB
  unsigned long long* mask2 = (unsigned long long*)alloc((size_t)RR * EE * (NN / 64) * 8);  // 4MB
  unsigned short* bufP = (unsigned short*)alloc((size_t)16 * NN * HDD * 2);    // 32MB bf16 partials
  unsigned short* bufC = (unsigned short*)alloc((size_t)RR * EE * HDD * 2);    // 4MB
  unsigned short* bufD = (unsigned short*)alloc((size_t)RR * EE * HDD * 2);    // 4MB
  unsigned short* bufE = (unsigned short*)alloc((size_t)RR * EE * HDD * 2);    // 4MB
  float* convout = (float*)alloc((size_t)NN * HDD * 4);                        // 4MB
  unsigned short* Xb    = (unsigned short*)alloc((size_t)NN * HDD * 2);        // 2MB
  unsigned short* XdvT  = (unsigned short*)alloc((size_t)RR * FF * NN * 2);    // 4MB
  unsigned short* hwdvT = (unsigned short*)alloc((size_t)RR * HDD * NN * 2);   // 8MB
  unsigned short* W1catT = (unsigned short*)alloc((size_t)RR * FF * HDD * 2);
  unsigned short* W2T    = (unsigned short*)alloc((size_t)RR * HDD * HDD * 2);
  unsigned short* W3T    = (unsigned short*)alloc((size_t)RR * HDD * FF * 2);

  // ---- prep (2 dispatches) ----
  k_prep1<<<4096 + 2048 + 34, 256, 0, stream>>>(H, rel, W1, W2, W3, imp,
                                                dvs, mask1, W1catT, W2T, W3T, de, cs);
  k_prep2<<<256 + 512, 256, 0, stream>>>(mask1, mask2, de, X, dvs, XdvT);

  // ---- layer 1 (128 -> 256) ----
  // raw1T[r][f][e] = sum_n XdvT[r][f][n] B2[e][n]   M=128,N=2048,K=4096, z=(r,SK8)
  k_gemm3<0, 1><<<dim3(1, EE / 128, RR * 8), 256, 0, stream>>>(
      XdvT, nullptr, NN, 8, NN, 0, (long)FF * NN, 0,
      bufP, (long)FF * EE, 8L * FF * EE, EE, mask2, NN / 64, EE, nullptr, 0);
  k_red_b<<<dim3((FF * EE) / 2048, RR), 256, 0, stream>>>(
      bufP, bufC, 8, (long)FF * EE, de, rel, nullptr);  // bufC = de^2 * raw1T
  // Hcat_raw[n][f] = sum_e B1[n][e] bufC[r][f][e]   M=4096,N=128,K=2048, z=(r,SK2)
  k_gemm3<1, 0><<<dim3(NN / 128, 1, RR * 2), 256, 0, stream>>>(
      nullptr, bufC, EE, 2, 0, EE, 0, (long)FF * EE,
      bufP, (long)NN * FF, 2L * NN * FF, FF, mask1, EE / 64, NN, nullptr, 0);
  k_red_hcatb<<<dim3((NN * FF) / 2048, RR), 256, 0, stream>>>(bufP, bufD, 2, dvs);  // Hcatb [4096][512]
  // convout = Hcatb @ W1cat   M=4096,N=256,K=512, SK=4 (b1 dropped: BN-invariant)
  k_gemm3<0, 0><<<dim3(NN / 128, HDD / 128, 4), 256, 0, stream>>>(
      bufD, W1catT, RR * FF, 4, RR * FF, RR * FF, 0, 0,
      bufP, (long)NN * HDD, 0, HDD, nullptr, 0, 0, nullptr, 0);
  k_redstats<<<NN / 32, 256, 0, stream>>>(bufP, convout, cs, cs + HDD, 4, nullptr, 0);
  k_bnlnelu<<<NN / 4, 256, 0, stream>>>(convout, cs, cs + HDD, bng, bnb, lng, lnb, Xb);

  // ---- layer 2 (256 -> 256), W2 applied FIRST (commutes with diag e-scales) ----
  // hwdvT[r][o][n] = dv[r][n] * sum_c W2T[r][o][c] Xb[n][c]   M=256,N=4096,K=256, z=r
  k_gemm3<0, 0><<<dim3(HDD / 128, NN / 128, RR), 256, 0, stream>>>(
      W2T, Xb, HDD, 1, HDD, HDD, (long)HDD * HDD, 0,
      hwdvT, 0, (long)HDD * NN, NN, nullptr, 0, 0, dvs, NN);
  // raw2[r][o][e] = sum_n hwdvT[r][o][n] B2[e][n]   M=256,N=2048,K=4096, z=(r,SK4)
  k_gemm3<0, 1><<<dim3(HDD / 128, EE / 128, RR * 4), 256, 0, stream>>>(
      hwdvT, nullptr, NN, 4, NN, 0, (long)HDD * NN, 0,
      bufP, (long)HDD * EE, 4L * HDD * EE, EE, mask2, NN / 64, EE, nullptr, 0);
  k_red_b<<<dim3((HDD * EE) / 2048, RR), 256, 0, stream>>>(
      bufP, bufE, 4, (long)HDD * EE, de, rel, cs);  // bufE = de^2 * raw2; zeroes cs for L2 stats
  // raw_out[n][o] = sum_e B1[n][e] bufE[r][o][e]   M=4096,N=256,K=2048, z=(r,SK2)
  k_gemm3<1, 0><<<dim3(NN / 128, HDD / 128, RR * 2), 256, 0, stream>>>(
      nullptr, bufE, EE, 2, 0, EE, 0, (long)HDD * EE,
      bufP, (long)NN * HDD, 2L * NN * HDD, HDD, mask1, EE / 64, NN, nullptr, 0);
  k_redstats<<<NN / 32, 256, 0, stream>>>(bufP, convout, cs, cs + HDD, 8, dvs, 1);
  k_bnlnelu<<<NN / 4, 256, 0, stream>>>(convout, cs, cs + HDD, bng + HDD, bnb + HDD, lng + HDD, lnb + HDD, Xb);

  // ---- layer 3 (256 -> 128), W3 applied first ----
  // ydvT[r][f][n] = (sum_c W3T[r][f][c] Xb[n][c]) * dv[r][n]   M=128,N=4096,K=256, z=r
  k_gemm3<0, 0><<<dim3(1, NN / 128, RR), 256, 0, stream>>>(
      W3T, Xb, HDD, 1, HDD, HDD, (long)FF * HDD, 0,
      bufD, 0, (long)FF * NN, NN, nullptr, 0, 0, dvs, NN);
  // raw3[r][f][e] = sum_n ydvT[r][f][n] B2[e][n]   M=128,N=2048,K=4096, z=(r,SK8)
  k_gemm3<0, 1><<<dim3(1, EE / 128, RR * 8), 256, 0, stream>>>(
      bufD, nullptr, NN, 8, NN, 0, (long)FF * NN, 0,
      bufP, (long)FF * EE, 8L * FF * EE, EE, mask2, NN / 64, EE, nullptr, 0);
  k_red_b<<<dim3((FF * EE) / 2048, RR), 256, 0, stream>>>(
      bufP, bufC, 8, (long)FF * EE, de, rel, nullptr);  // bufC = de^2 * raw3
  // P[z] = B1[r] @ bufC[r]   M=4096,N=128,K=2048, z=(r,SK2)
  k_gemm3<1, 0><<<dim3(NN / 128, 1, RR * 2), 256, 0, stream>>>(
      nullptr, bufC, EE, 2, 0, EE, 0, (long)FF * EE,
      bufP, (long)NN * FF, 2L * NN * FF, FF, mask1, EE / 64, NN, nullptr, 0);
  // d_out = X + b3 + sum_z dv[r][n] * P[z]
  k_red_out<<<(NN * FF) / 1024, 256, 0, stream>>>(bufP, X, b3, (float*)d_out, 8, dvs);
}